// Round 7
// baseline (257.026 us; speedup 1.0000x reference)
//
#include <hip/hip_runtime.h>

#define BATCH   262144
#define IN_DIM  28
#define HID     128
#define LAT     64
#define NCODES  512
#define NBLK    1024            // 256 rows per block (8 waves x 32 rows)
#define NWAVE   (NBLK * 8)

#define BLOB_SHORTS 57344       // bf16 table region (shorts)
#define BLOB_F32    864         // fp32 region (e2 + biases)
#define BLOB_BYTES  (BLOB_SHORTS * 2 + BLOB_F32 * 4)   // 118144
#define ACT_BASE    (BLOB_BYTES / 2)                    // short offset 59072
#define LDS_BYTES   (BLOB_BYTES + 8 * 2048 * 2)         // 150912

typedef short v8s __attribute__((ext_vector_type(8)));
typedef float v4f __attribute__((ext_vector_type(4)));

union v8u { v8s s; uint4 u; };

__device__ __forceinline__ unsigned short f2bf(float f) {   // RNE (prep only)
  unsigned u = __float_as_uint(f);
  u += 0x7fffu + ((u >> 16) & 1u);
  return (unsigned short)(u >> 16);
}
// truncating f32->bf16 (1 op; accuracy budget has 12x headroom vs RNE)
__device__ __forceinline__ unsigned short hi16(float f) {
  return (unsigned short)(__float_as_uint(f) >> 16);
}
// pack two truncated bf16 (lo, hi) in ONE v_perm_b32
__device__ __forceinline__ unsigned pk(float hi, float lo) {
  return __builtin_amdgcn_perm(__float_as_uint(hi), __float_as_uint(lo), 0x07060302u);
}

// Bank-swizzled table offset (shorts): 16B col-blocks XOR-permuted by row.
__device__ __forceinline__ int toff(int base, int row, int col, int SB) {
  return base + row * (SB * 8) + ((((col >> 3) ^ row) & (SB - 1)) << 3) + (col & 7);
}
// XOR-swizzled 16-row activation tile (per wave), offsets in shorts.
__device__ __forceinline__ int swz(int row, int col) {
  int g = col >> 3;
  return (g * 16 + ((row ^ g) & 15)) * 8 + (col & 7);
}

// Blob layout (short offsets):
//   lw1  @0      [128 n][32 k]  SB=4   enc_w1^T (k>=28 zero)
//   lw2  @4096   [64 n][128 k]  SB=16  enc_w2^T
//   lcb  @12288  [512 c][64 d]  SB=8   bf16(-2*codebook)   <-- scaled!
//   ld1  @45056  [128 n][64 k]  SB=8   bf16(-0.5*dec_w1^T) <-- scaled!
//   ld2  @53248  [32 n][128 k]  SB=16  dec_w2^T (n>=28 zero)
// fp32 @ byte 114688: e2[512], b1[128], b2[64], db1[128], db2[32 pad0]
__global__ __launch_bounds__(256) void vq_prep(
    const float* __restrict__ ew1, const float* __restrict__ eb1,
    const float* __restrict__ ew2, const float* __restrict__ eb2,
    const float* __restrict__ cb,  const float* __restrict__ dw1,
    const float* __restrict__ db1, const float* __restrict__ dw2,
    const float* __restrict__ db2,
    unsigned short* __restrict__ blob) {
  int i = blockIdx.x * 256 + threadIdx.x;
  float* fb = (float*)(blob + BLOB_SHORTS);
  if (i < 4096) {                       // lw1
    int row = i >> 5, col = i & 31;
    float v = (col < IN_DIM) ? ew1[col * HID + row] : 0.f;
    blob[toff(0, row, col, 4)] = f2bf(v);
  } else if (i < 12288) {               // lw2
    int j = i - 4096; int row = j >> 7, col = j & 127;
    blob[toff(4096, row, col, 16)] = f2bf(ew2[col * LAT + row]);
  } else if (i < 45056) {               // lcb = -2*cb
    int j = i - 12288; int row = j >> 6, col = j & 63;
    blob[toff(12288, row, col, 8)] = f2bf(-2.0f * cb[j]);
  } else if (i < 53248) {               // ld1 = -0.5*dec_w1^T  (exact scale)
    int j = i - 45056; int row = j >> 6, col = j & 63;
    blob[toff(45056, row, col, 8)] = f2bf(-0.5f * dw1[col * HID + row]);
  } else if (i < 57344) {               // ld2
    int j = i - 53248; int row = j >> 7, col = j & 127;
    float v = (row < IN_DIM) ? dw2[col * IN_DIM + row] : 0.f;
    blob[toff(53248, row, col, 16)] = f2bf(v);
  } else if (i < 57344 + 512) {         // e2
    int c = i - 57344;
    float s = 0.f;
    for (int d = 0; d < LAT; ++d) { float v = cb[c * LAT + d]; s += v * v; }
    fb[c] = s;
  } else if (i < 57344 + 640) {
    fb[i - 57344] = eb1[i - 57344 - 512];
  } else if (i < 57344 + 704) {
    fb[i - 57344] = eb2[i - 57344 - 640];
  } else if (i < 57344 + 832) {
    fb[i - 57344] = db1[i - 57344 - 704];
  } else if (i < 57344 + 864) {
    int k = i - 57344 - 832;
    fb[i - 57344] = (k < IN_DIM) ? db2[k] : 0.f;
  }
}

// ---------------- fused main kernel ----------------
// Tables in LDS (round-5 win), 8 waves/block (round-6 win). Round-7: each
// wave owns 32 rows as TWO register-resident 16-row tiles -> stage-2/argmin/
// stage-5/stage-6 table fragments read ONCE from LDS and shared across both
// tiles (halves dominant table-b128 traffic, doubles in-wave MFMA ILP);
// perm-packed / hi16-truncated bf16 conversion (1 VALU per 1-2 values).
__global__ __launch_bounds__(512, 2) void vq_main(
    const float* __restrict__ x,
    const unsigned short* __restrict__ blob,
    float* __restrict__ out, float* __restrict__ partials) {

  extern __shared__ __align__(16) char smem[];
  unsigned short* L  = (unsigned short*)smem;
  float*          LF = (float*)(smem + BLOB_SHORTS * 2);

  const int tid  = threadIdx.x;
  const int wave = tid >> 6;
  const int lane = tid & 63;
  const int quad = lane >> 4;
  const int lm   = lane & 15;

  // ---- stage tables into LDS (one-time) ----
  {
    const float4* src = (const float4*)blob;
    float4* dst = (float4*)smem;
#pragma unroll
    for (int it = 0; it < 15; ++it) {
      int idx = it * 512 + tid;
      if (idx < BLOB_BYTES / 16) dst[idx] = src[idx];
    }
  }
  __syncthreads();

  unsigned short* A = L + ACT_BASE + wave * 2048;
  const int rbase = blockIdx.x * 256 + wave * 32;
  float racc = 0.f, vqacc = 0.f;

  // ---- stage 1: H = relu(X @ W1 + b1), per tile (shared act buffer) ----
  v8s ha[2][4];
#pragma unroll
  for (int t = 0; t < 2; ++t) {
    v8u a1;
    {
      const float* xp = x + (size_t)(rbase + t * 16 + lm) * IN_DIM + quad * 8;
      float4 v0 = *(const float4*)xp;
      float4 v1 = {0.f, 0.f, 0.f, 0.f};
      if (quad != 3) v1 = *(const float4*)(xp + 4);
      a1.u.x = pk(v0.y, v0.x); a1.u.y = pk(v0.w, v0.z);
      a1.u.z = pk(v1.y, v1.x); a1.u.w = pk(v1.w, v1.z);
    }
#pragma unroll
    for (int nt = 0; nt < 8; ++nt) {
      int row = nt * 16 + lm;
      v8s frag = *(const v8s*)&L[toff(0, row, quad * 8, 4)];
      float bv = LF[512 + row];
      v4f seed = {bv, bv, bv, bv};
      v4f acc = __builtin_amdgcn_mfma_f32_16x16x32_bf16(a1.s, frag, seed, 0, 0, 0);
#pragma unroll
      for (int r = 0; r < 4; ++r)
        A[swz(quad * 4 + r, row)] = hi16(fmaxf(acc[r], 0.f));
    }
#pragma unroll
    for (int ks = 0; ks < 4; ++ks)
      ha[t][ks] = *(const v8s*)&A[swz(lm, ks * 32 + quad * 8)];
  }

  // ---- stage 2: Z = H @ W2 + b2 (B-frags shared across tiles) ----
  v4f accz[2][4];
#pragma unroll
  for (int nt = 0; nt < 4; ++nt) {
    int row = nt * 16 + lm;
    float bv = LF[640 + row];
    accz[0][nt] = (v4f){bv, bv, bv, bv};
    accz[1][nt] = (v4f){bv, bv, bv, bv};
#pragma unroll
    for (int ks = 0; ks < 4; ++ks) {
      v8s frag = *(const v8s*)&L[toff(4096, row, ks * 32 + quad * 8, 16)];
      accz[0][nt] = __builtin_amdgcn_mfma_f32_16x16x32_bf16(ha[0][ks], frag, accz[0][nt], 0, 0, 0);
      accz[1][nt] = __builtin_amdgcn_mfma_f32_16x16x32_bf16(ha[1][ks], frag, accz[1][nt], 0, 0, 0);
    }
  }

  // ---- z store (plain bf16 z; table holds -2e) + A-frags ----
  v8s za[2][2];
#pragma unroll
  for (int t = 0; t < 2; ++t) {
#pragma unroll
    for (int nt = 0; nt < 4; ++nt)
#pragma unroll
      for (int r = 0; r < 4; ++r)
        A[swz(quad * 4 + r, nt * 16 + lm)] = hi16(accz[t][nt][r]);
    za[t][0] = *(const v8s*)&A[swz(lm, quad * 8)];
    za[t][1] = *(const v8s*)&A[swz(lm, 32 + quad * 8)];
  }

  // ---- argmin: dist = e2 + z.(-2e), codebook frags shared across tiles ----
  float bd[2][4]; int bc[2][4];
#pragma unroll
  for (int t = 0; t < 2; ++t)
#pragma unroll
    for (int r = 0; r < 4; ++r) { bd[t][r] = 3.4e38f; bc[t][r] = 0x7fffffff; }
#pragma unroll
  for (int ct = 0; ct < 32; ++ct) {
    int row = ct * 16 + lm;
    v8s cb0 = *(const v8s*)&L[toff(12288, row, quad * 8, 8)];
    v8s cb1 = *(const v8s*)&L[toff(12288, row, 32 + quad * 8, 8)];
    float ev = LF[row];
    v4f seed = {ev, ev, ev, ev};
#pragma unroll
    for (int t = 0; t < 2; ++t) {
      v4f acc = __builtin_amdgcn_mfma_f32_16x16x32_bf16(za[t][0], cb0, seed, 0, 0, 0);
      acc = __builtin_amdgcn_mfma_f32_16x16x32_bf16(za[t][1], cb1, acc, 0, 0, 0);
#pragma unroll
      for (int r = 0; r < 4; ++r)
        if (acc[r] < bd[t][r]) { bd[t][r] = acc[r]; bc[t][r] = row; }  // ascending -> lowest idx on tie
    }
  }

  // ---- per-tile reduce: argmin + z^2, vq partial, idx broadcast ----
  int idxv[2];
#pragma unroll
  for (int t = 0; t < 2; ++t) {
    float z2p[4];
#pragma unroll
    for (int r = 0; r < 4; ++r)
      z2p[r] = accz[t][0][r] * accz[t][0][r] + accz[t][1][r] * accz[t][1][r]
             + accz[t][2][r] * accz[t][2][r] + accz[t][3][r] * accz[t][3][r];
#pragma unroll
    for (int off = 1; off < 16; off <<= 1) {
#pragma unroll
      for (int r = 0; r < 4; ++r) {
        float od = __shfl_xor(bd[t][r], off, 64);
        int   oc = __shfl_xor(bc[t][r], off, 64);
        if (od < bd[t][r] || (od == bd[t][r] && oc < bc[t][r])) { bd[t][r] = od; bc[t][r] = oc; }
        z2p[r] += __shfl_xor(z2p[r], off, 64);
      }
    }
    if (lm == 0) {
#pragma unroll
      for (int r = 0; r < 4; ++r) vqacc += z2p[r] + bd[t][r];   // ||z-q||^2
    }
    int i0 = __shfl(bc[t][0], (lm >> 2) << 4, 64);
    int i1 = __shfl(bc[t][1], (lm >> 2) << 4, 64);
    int i2 = __shfl(bc[t][2], (lm >> 2) << 4, 64);
    int i3 = __shfl(bc[t][3], (lm >> 2) << 4, 64);
    int sel = lm & 3;
    idxv[t] = sel == 0 ? i0 : sel == 1 ? i1 : sel == 2 ? i2 : i3;
  }

  // ---- stage 5: HD = relu(Q @ DW1 + db1); A = -2q, W pre-scaled by -0.5 ----
  v8s hd[2][4];
  {
    v8s qa[2][2];
#pragma unroll
    for (int t = 0; t < 2; ++t) {
      qa[t][0] = *(const v8s*)&L[toff(12288, idxv[t], quad * 8, 8)];
      qa[t][1] = *(const v8s*)&L[toff(12288, idxv[t], 32 + quad * 8, 8)];
    }
    v4f a5[2][8];
#pragma unroll
    for (int nt = 0; nt < 8; ++nt) {
      int row = nt * 16 + lm;
      v8s b0 = *(const v8s*)&L[toff(45056, row, quad * 8, 8)];
      v8s b1 = *(const v8s*)&L[toff(45056, row, 32 + quad * 8, 8)];
      float bv = LF[704 + row];
      v4f seed = {bv, bv, bv, bv};
#pragma unroll
      for (int t = 0; t < 2; ++t) {
        a5[t][nt] = __builtin_amdgcn_mfma_f32_16x16x32_bf16(qa[t][0], b0, seed, 0, 0, 0);
        a5[t][nt] = __builtin_amdgcn_mfma_f32_16x16x32_bf16(qa[t][1], b1, a5[t][nt], 0, 0, 0);
      }
    }
#pragma unroll
    for (int t = 0; t < 2; ++t) {
#pragma unroll
      for (int nt = 0; nt < 8; ++nt)
#pragma unroll
        for (int r = 0; r < 4; ++r)
          A[swz(quad * 4 + r, nt * 16 + lm)] = hi16(fmaxf(a5[t][nt][r], 0.f));
#pragma unroll
      for (int ks = 0; ks < 4; ++ks)
        hd[t][ks] = *(const v8s*)&A[swz(lm, ks * 32 + quad * 8)];
    }
  }

  // ---- stage 6: R = HD @ DW2 + db2 (B shared); store + recon loss ----
  {
    v4f a6[2][2];
#pragma unroll
    for (int nt = 0; nt < 2; ++nt) {
      int row = nt * 16 + lm;
      float bv = LF[832 + row];
      a6[0][nt] = (v4f){bv, bv, bv, bv};
      a6[1][nt] = (v4f){bv, bv, bv, bv};
#pragma unroll
      for (int ks = 0; ks < 4; ++ks) {
        v8s frag = *(const v8s*)&L[toff(53248, row, ks * 32 + quad * 8, 16)];
        a6[0][nt] = __builtin_amdgcn_mfma_f32_16x16x32_bf16(hd[0][ks], frag, a6[0][nt], 0, 0, 0);
        a6[1][nt] = __builtin_amdgcn_mfma_f32_16x16x32_bf16(hd[1][ks], frag, a6[1][nt], 0, 0, 0);
      }
    }
#pragma unroll
    for (int t = 0; t < 2; ++t)
#pragma unroll
      for (int nt = 0; nt < 2; ++nt) {
        int n = nt * 16 + lm;
        bool valid = (n < IN_DIM);
#pragma unroll
        for (int r = 0; r < 4; ++r) {
          float rec = a6[t][nt][r];
          if (valid) {
            size_t o = (size_t)(rbase + t * 16 + quad * 4 + r) * IN_DIM + n;
            out[o] = rec;
            float dv = rec - x[o];
            racc += dv * dv;
          }
        }
      }
  }

  // ---- per-wave butterfly, per-wave partial store (no atomics) ----
#pragma unroll
  for (int off = 1; off < 64; off <<= 1) {
    racc  += __shfl_xor(racc, off, 64);
    vqacc += __shfl_xor(vqacc, off, 64);
  }
  if (lane == 0) {
    size_t w = (size_t)blockIdx.x * 8 + wave;
    partials[w * 2]     = racc;
    partials[w * 2 + 1] = vqacc;
  }
}

// ---------------- finalize: reduce per-wave partials, write scalars ----------------
__global__ __launch_bounds__(256) void vq_fin(const float* __restrict__ partials,
                                              float* __restrict__ out) {
  float r = 0.f, v = 0.f;
  for (int i = threadIdx.x; i < NWAVE; i += 256) {
    r += partials[2 * i];
    v += partials[2 * i + 1];
  }
#pragma unroll
  for (int off = 1; off < 64; off <<= 1) {
    r += __shfl_xor(r, off, 64);
    v += __shfl_xor(v, off, 64);
  }
  __shared__ float s[4][2];
  int w = threadIdx.x >> 6;
  if ((threadIdx.x & 63) == 0) { s[w][0] = r; s[w][1] = v; }
  __syncthreads();
  if (threadIdx.x == 0) {
    float R = s[0][0] + s[1][0] + s[2][0] + s[3][0];
    float V = s[0][1] + s[1][1] + s[2][1] + s[3][1];
    out[7340032] = R * (1.0f / 7340032.0f);          // recon_loss = S / (B*28)
    out[7340033] = V * (1.25f / 16777216.0f);        // vq_loss = 1.25 * S / (B*64)
  }
}

extern "C" void kernel_launch(void* const* d_in, const int* in_sizes, int n_in,
                              void* d_out, int out_size, void* d_ws, size_t ws_size,
                              hipStream_t stream) {
  const float* x   = (const float*)d_in[0];
  const float* ew1 = (const float*)d_in[1];
  const float* eb1 = (const float*)d_in[2];
  const float* ew2 = (const float*)d_in[3];
  const float* eb2 = (const float*)d_in[4];
  const float* cb  = (const float*)d_in[5];
  const float* dw1 = (const float*)d_in[6];
  const float* db1 = (const float*)d_in[7];
  const float* dw2 = (const float*)d_in[8];
  const float* db2 = (const float*)d_in[9];

  char* ws = (char*)d_ws;
  unsigned short* blob = (unsigned short*)(ws + 0);   // 118144 B
  float* partials = (float*)(ws + 118272);            // 65536 B (8192*2 f32)

  float* out = (float*)d_out;

  // allow >64 KB dynamic LDS (gfx950 workgroup max is 160 KB)
  (void)hipFuncSetAttribute((const void*)vq_main,
                            hipFuncAttributeMaxDynamicSharedMemorySize, LDS_BYTES);

  vq_prep<<<228, 256, 0, stream>>>(ew1, eb1, ew2, eb2, cb, dw1, db1, dw2, db2, blob);
  vq_main<<<NBLK, 512, LDS_BYTES, stream>>>(x, blob, out, partials);
  vq_fin<<<1, 256, 0, stream>>>(partials, out);
}

// Round 8
// 175.031 us; speedup vs baseline: 1.4685x; 1.4685x over previous
//
#include <hip/hip_runtime.h>

#define BATCH   262144
#define IN_DIM  28
#define HID     128
#define LAT     64
#define NCODES  512
#define NBLK    1024            // 256 rows per block (8 waves x 32 rows)
#define NWAVE   (NBLK * 8)

#define BLOB_SHORTS 57344       // bf16 table region (shorts)
#define BLOB_F32    864         // fp32 region (e2 + biases)
#define BLOB_BYTES  (BLOB_SHORTS * 2 + BLOB_F32 * 4)   // 118144
#define ACT_BASE    (BLOB_BYTES / 2)                    // short offset 59072
#define LDS_BYTES   (BLOB_BYTES + 8 * 2048 * 2)         // 150912

typedef short v8s __attribute__((ext_vector_type(8)));
typedef float v4f __attribute__((ext_vector_type(4)));

union v8u { v8s s; uint4 u; };

__device__ __forceinline__ unsigned short f2bf(float f) {   // RNE (prep only)
  unsigned u = __float_as_uint(f);
  u += 0x7fffu + ((u >> 16) & 1u);
  return (unsigned short)(u >> 16);
}
// truncating f32->bf16 (1 op; validated round 7: absmax 0.0015 < thr 0.020)
__device__ __forceinline__ unsigned short hi16(float f) {
  return (unsigned short)(__float_as_uint(f) >> 16);
}
// pack two truncated bf16 (lo, hi) in ONE v_perm_b32
__device__ __forceinline__ unsigned pk(float hi, float lo) {
  return __builtin_amdgcn_perm(__float_as_uint(hi), __float_as_uint(lo), 0x07060302u);
}

// Bank-swizzled table offset (shorts): 16B col-blocks XOR-permuted by row.
__device__ __forceinline__ int toff(int base, int row, int col, int SB) {
  return base + row * (SB * 8) + ((((col >> 3) ^ row) & (SB - 1)) << 3) + (col & 7);
}
// XOR-swizzled 16-row activation tile (per wave), offsets in shorts.
__device__ __forceinline__ int swz(int row, int col) {
  int g = col >> 3;
  return (g * 16 + ((row ^ g) & 15)) * 8 + (col & 7);
}

// Blob layout (short offsets):
//   lw1  @0      [128 n][32 k]  SB=4   enc_w1^T (k>=28 zero)
//   lw2  @4096   [64 n][128 k]  SB=16  enc_w2^T
//   lcb  @12288  [512 c][64 d]  SB=8   bf16(-2*codebook)   <-- scaled
//   ld1  @45056  [128 n][64 k]  SB=8   bf16(-0.5*dec_w1^T) <-- scaled (cancels)
//   ld2  @53248  [32 n][128 k]  SB=16  dec_w2^T (n>=28 zero)
// fp32 @ byte 114688: e2[512], b1[128], b2[64], db1[128], db2[32 pad0]
__global__ __launch_bounds__(256) void vq_prep(
    const float* __restrict__ ew1, const float* __restrict__ eb1,
    const float* __restrict__ ew2, const float* __restrict__ eb2,
    const float* __restrict__ cb,  const float* __restrict__ dw1,
    const float* __restrict__ db1, const float* __restrict__ dw2,
    const float* __restrict__ db2,
    unsigned short* __restrict__ blob) {
  int i = blockIdx.x * 256 + threadIdx.x;
  float* fb = (float*)(blob + BLOB_SHORTS);
  if (i < 4096) {                       // lw1
    int row = i >> 5, col = i & 31;
    float v = (col < IN_DIM) ? ew1[col * HID + row] : 0.f;
    blob[toff(0, row, col, 4)] = f2bf(v);
  } else if (i < 12288) {               // lw2
    int j = i - 4096; int row = j >> 7, col = j & 127;
    blob[toff(4096, row, col, 16)] = f2bf(ew2[col * LAT + row]);
  } else if (i < 45056) {               // lcb = -2*cb
    int j = i - 12288; int row = j >> 6, col = j & 63;
    blob[toff(12288, row, col, 8)] = f2bf(-2.0f * cb[j]);
  } else if (i < 53248) {               // ld1 = -0.5*dec_w1^T  (exact scale)
    int j = i - 45056; int row = j >> 6, col = j & 63;
    blob[toff(45056, row, col, 8)] = f2bf(-0.5f * dw1[col * HID + row]);
  } else if (i < 57344) {               // ld2
    int j = i - 53248; int row = j >> 7, col = j & 127;
    float v = (row < IN_DIM) ? dw2[col * IN_DIM + row] : 0.f;
    blob[toff(53248, row, col, 16)] = f2bf(v);
  } else if (i < 57344 + 512) {         // e2
    int c = i - 57344;
    float s = 0.f;
    for (int d = 0; d < LAT; ++d) { float v = cb[c * LAT + d]; s += v * v; }
    fb[c] = s;
  } else if (i < 57344 + 640) {
    fb[i - 57344] = eb1[i - 57344 - 512];
  } else if (i < 57344 + 704) {
    fb[i - 57344] = eb2[i - 57344 - 640];
  } else if (i < 57344 + 832) {
    fb[i - 57344] = db1[i - 57344 - 704];
  } else if (i < 57344 + 864) {
    int k = i - 57344 - 832;
    fb[i - 57344] = (k < IN_DIM) ? db2[k] : 0.f;
  }
}

// ---------------- fused main kernel ----------------
// Round-6 skeleton (tables in LDS, 8 waves/block, per-tile stages 1/2/5/6 —
// low register pressure). Round-8 delta: the ARGMIN loop only is shared
// across the wave's two 16-row tiles (codebook frags read once, 2 MFMA
// chains) — live set there is just za[2][2]+bd/bc+z2p, so no spill (round-7
// lesson: stage-5 sharing needed 64 acc VGPRs -> scratch catastrophe).
__global__ __launch_bounds__(512, 1) void vq_main(
    const float* __restrict__ x,
    const unsigned short* __restrict__ blob,
    float* __restrict__ out, float* __restrict__ partials) {

  extern __shared__ __align__(16) char smem[];
  unsigned short* L  = (unsigned short*)smem;
  float*          LF = (float*)(smem + BLOB_SHORTS * 2);

  const int tid  = threadIdx.x;
  const int wave = tid >> 6;
  const int lane = tid & 63;
  const int quad = lane >> 4;
  const int lm   = lane & 15;

  // ---- stage tables into LDS (one-time) ----
  {
    const float4* src = (const float4*)blob;
    float4* dst = (float4*)smem;
#pragma unroll
    for (int it = 0; it < 15; ++it) {
      int idx = it * 512 + tid;
      if (idx < BLOB_BYTES / 16) dst[idx] = src[idx];
    }
  }
  __syncthreads();

  unsigned short* A = L + ACT_BASE + wave * 2048;
  const int rbase = blockIdx.x * 256 + wave * 32;
  float racc = 0.f, vqacc = 0.f;

  // ---- stages 1+2 per tile (round-6 form); z kept in accz ----
  v4f accz[2][4];
#pragma unroll
  for (int t = 0; t < 2; ++t) {
    v8u a1;
    {
      const float* xp = x + (size_t)(rbase + t * 16 + lm) * IN_DIM + quad * 8;
      float4 v0 = *(const float4*)xp;
      float4 v1 = {0.f, 0.f, 0.f, 0.f};
      if (quad != 3) v1 = *(const float4*)(xp + 4);
      a1.u.x = pk(v0.y, v0.x); a1.u.y = pk(v0.w, v0.z);
      a1.u.z = pk(v1.y, v1.x); a1.u.w = pk(v1.w, v1.z);
    }
#pragma unroll
    for (int nt = 0; nt < 8; ++nt) {
      int row = nt * 16 + lm;
      v8s frag = *(const v8s*)&L[toff(0, row, quad * 8, 4)];
      float bv = LF[512 + row];
      v4f seed = {bv, bv, bv, bv};
      v4f acc = __builtin_amdgcn_mfma_f32_16x16x32_bf16(a1.s, frag, seed, 0, 0, 0);
#pragma unroll
      for (int r = 0; r < 4; ++r)
        A[swz(quad * 4 + r, row)] = hi16(fmaxf(acc[r], 0.f));
    }
    v8s ha[4];
#pragma unroll
    for (int ks = 0; ks < 4; ++ks)
      ha[ks] = *(const v8s*)&A[swz(lm, ks * 32 + quad * 8)];
#pragma unroll
    for (int nt = 0; nt < 4; ++nt) {
      int row = nt * 16 + lm;
      float bv = LF[640 + row];
      accz[t][nt] = (v4f){bv, bv, bv, bv};
#pragma unroll
      for (int ks = 0; ks < 4; ++ks) {
        v8s frag = *(const v8s*)&L[toff(4096, row, ks * 32 + quad * 8, 16)];
        accz[t][nt] = __builtin_amdgcn_mfma_f32_16x16x32_bf16(ha[ks], frag, accz[t][nt], 0, 0, 0);
      }
    }
  }

  // ---- both z tiles -> act buffer halves (z is 16x64 = 1024 shorts); z2p ----
  float z2p[2][4];
  v8s za[2][2];
#pragma unroll
  for (int t = 0; t < 2; ++t) {
#pragma unroll
    for (int nt = 0; nt < 4; ++nt)
#pragma unroll
      for (int r = 0; r < 4; ++r)
        A[t * 1024 + swz(quad * 4 + r, nt * 16 + lm)] = hi16(accz[t][nt][r]);
#pragma unroll
    for (int r = 0; r < 4; ++r)
      z2p[t][r] = accz[t][0][r] * accz[t][0][r] + accz[t][1][r] * accz[t][1][r]
                + accz[t][2][r] * accz[t][2][r] + accz[t][3][r] * accz[t][3][r];
  }
#pragma unroll
  for (int t = 0; t < 2; ++t) {
    za[t][0] = *(const v8s*)&A[t * 1024 + swz(lm, quad * 8)];
    za[t][1] = *(const v8s*)&A[t * 1024 + swz(lm, 32 + quad * 8)];
  }

  // ---- argmin SHARED across tiles: dist = e2 + z.(-2e); cb frags read once ----
  float bd[2][4]; int bc[2][4];
#pragma unroll
  for (int t = 0; t < 2; ++t)
#pragma unroll
    for (int r = 0; r < 4; ++r) { bd[t][r] = 3.4e38f; bc[t][r] = 0x7fffffff; }
#pragma unroll 4
  for (int ct = 0; ct < 32; ++ct) {
    int row = ct * 16 + lm;
    v8s cb0 = *(const v8s*)&L[toff(12288, row, quad * 8, 8)];
    v8s cb1 = *(const v8s*)&L[toff(12288, row, 32 + quad * 8, 8)];
    float ev = LF[row];
    v4f seed = {ev, ev, ev, ev};
#pragma unroll
    for (int t = 0; t < 2; ++t) {
      v4f acc = __builtin_amdgcn_mfma_f32_16x16x32_bf16(za[t][0], cb0, seed, 0, 0, 0);
      acc = __builtin_amdgcn_mfma_f32_16x16x32_bf16(za[t][1], cb1, acc, 0, 0, 0);
#pragma unroll
      for (int r = 0; r < 4; ++r)
        if (acc[r] < bd[t][r]) { bd[t][r] = acc[r]; bc[t][r] = row; }  // ascending -> lowest idx on tie
    }
  }

  // ---- per-tile reduce: argmin + z^2, vq partial, idx broadcast ----
  int idxv[2];
#pragma unroll
  for (int t = 0; t < 2; ++t) {
#pragma unroll
    for (int off = 1; off < 16; off <<= 1) {
#pragma unroll
      for (int r = 0; r < 4; ++r) {
        float od = __shfl_xor(bd[t][r], off, 64);
        int   oc = __shfl_xor(bc[t][r], off, 64);
        if (od < bd[t][r] || (od == bd[t][r] && oc < bc[t][r])) { bd[t][r] = od; bc[t][r] = oc; }
        z2p[t][r] += __shfl_xor(z2p[t][r], off, 64);
      }
    }
    if (lm == 0) {
#pragma unroll
      for (int r = 0; r < 4; ++r) vqacc += z2p[t][r] + bd[t][r];   // ||z-q||^2
    }
    int i0 = __shfl(bc[t][0], (lm >> 2) << 4, 64);
    int i1 = __shfl(bc[t][1], (lm >> 2) << 4, 64);
    int i2 = __shfl(bc[t][2], (lm >> 2) << 4, 64);
    int i3 = __shfl(bc[t][3], (lm >> 2) << 4, 64);
    int sel = lm & 3;
    idxv[t] = sel == 0 ? i0 : sel == 1 ? i1 : sel == 2 ? i2 : i3;
  }

  // ---- stages 5+6 per tile (round-6 form, low register pressure) ----
#pragma unroll
  for (int t = 0; t < 2; ++t) {
    // stage 5: HD = relu(Q @ DW1 + db1); A-op = -2q, W pre-scaled by -0.5
    v8s qa0 = *(const v8s*)&L[toff(12288, idxv[t], quad * 8, 8)];
    v8s qa1 = *(const v8s*)&L[toff(12288, idxv[t], 32 + quad * 8, 8)];
#pragma unroll
    for (int nt = 0; nt < 8; ++nt) {
      int row = nt * 16 + lm;
      v8s b0 = *(const v8s*)&L[toff(45056, row, quad * 8, 8)];
      v8s b1 = *(const v8s*)&L[toff(45056, row, 32 + quad * 8, 8)];
      float bv = LF[704 + row];
      v4f seed = {bv, bv, bv, bv};
      v4f acc = __builtin_amdgcn_mfma_f32_16x16x32_bf16(qa0, b0, seed, 0, 0, 0);
      acc = __builtin_amdgcn_mfma_f32_16x16x32_bf16(qa1, b1, acc, 0, 0, 0);
#pragma unroll
      for (int r = 0; r < 4; ++r)
        A[swz(quad * 4 + r, row)] = hi16(fmaxf(acc[r], 0.f));
    }
    v8s hd[4];
#pragma unroll
    for (int ks = 0; ks < 4; ++ks)
      hd[ks] = *(const v8s*)&A[swz(lm, ks * 32 + quad * 8)];
    // stage 6: R = HD @ DW2 + db2; store + recon loss
    v4f a6[2];
#pragma unroll
    for (int nt = 0; nt < 2; ++nt) {
      int row = nt * 16 + lm;
      float bv = LF[832 + row];
      a6[nt] = (v4f){bv, bv, bv, bv};
#pragma unroll
      for (int ks = 0; ks < 4; ++ks) {
        v8s frag = *(const v8s*)&L[toff(53248, row, ks * 32 + quad * 8, 16)];
        a6[nt] = __builtin_amdgcn_mfma_f32_16x16x32_bf16(hd[ks], frag, a6[nt], 0, 0, 0);
      }
    }
#pragma unroll
    for (int nt = 0; nt < 2; ++nt) {
      int n = nt * 16 + lm;
      bool valid = (n < IN_DIM);
#pragma unroll
      for (int r = 0; r < 4; ++r) {
        float rec = a6[nt][r];
        if (valid) {
          size_t o = (size_t)(rbase + t * 16 + quad * 4 + r) * IN_DIM + n;
          out[o] = rec;
          float dv = rec - x[o];
          racc += dv * dv;
        }
      }
    }
  }

  // ---- per-wave butterfly, per-wave partial store (no atomics) ----
#pragma unroll
  for (int off = 1; off < 64; off <<= 1) {
    racc  += __shfl_xor(racc, off, 64);
    vqacc += __shfl_xor(vqacc, off, 64);
  }
  if (lane == 0) {
    size_t w = (size_t)blockIdx.x * 8 + wave;
    partials[w * 2]     = racc;
    partials[w * 2 + 1] = vqacc;
  }
}

// ---------------- finalize: reduce per-wave partials, write scalars ----------------
__global__ __launch_bounds__(256) void vq_fin(const float* __restrict__ partials,
                                              float* __restrict__ out) {
  float r = 0.f, v = 0.f;
  for (int i = threadIdx.x; i < NWAVE; i += 256) {
    r += partials[2 * i];
    v += partials[2 * i + 1];
  }
#pragma unroll
  for (int off = 1; off < 64; off <<= 1) {
    r += __shfl_xor(r, off, 64);
    v += __shfl_xor(v, off, 64);
  }
  __shared__ float s[4][2];
  int w = threadIdx.x >> 6;
  if ((threadIdx.x & 63) == 0) { s[w][0] = r; s[w][1] = v; }
  __syncthreads();
  if (threadIdx.x == 0) {
    float R = s[0][0] + s[1][0] + s[2][0] + s[3][0];
    float V = s[0][1] + s[1][1] + s[2][1] + s[3][1];
    out[7340032] = R * (1.0f / 7340032.0f);          // recon_loss = S / (B*28)
    out[7340033] = V * (1.25f / 16777216.0f);        // vq_loss = 1.25 * S / (B*64)
  }
}

extern "C" void kernel_launch(void* const* d_in, const int* in_sizes, int n_in,
                              void* d_out, int out_size, void* d_ws, size_t ws_size,
                              hipStream_t stream) {
  const float* x   = (const float*)d_in[0];
  const float* ew1 = (const float*)d_in[1];
  const float* eb1 = (const float*)d_in[2];
  const float* ew2 = (const float*)d_in[3];
  const float* eb2 = (const float*)d_in[4];
  const float* cb  = (const float*)d_in[5];
  const float* dw1 = (const float*)d_in[6];
  const float* db1 = (const float*)d_in[7];
  const float* dw2 = (const float*)d_in[8];
  const float* db2 = (const float*)d_in[9];

  char* ws = (char*)d_ws;
  unsigned short* blob = (unsigned short*)(ws + 0);   // 118144 B
  float* partials = (float*)(ws + 118272);            // 65536 B (8192*2 f32)

  float* out = (float*)d_out;

  // allow >64 KB dynamic LDS (gfx950 workgroup max is 160 KB)
  (void)hipFuncSetAttribute((const void*)vq_main,
                            hipFuncAttributeMaxDynamicSharedMemorySize, LDS_BYTES);

  vq_prep<<<228, 256, 0, stream>>>(ew1, eb1, ew2, eb2, cb, dw1, db1, dw2, db2, blob);
  vq_main<<<NBLK, 512, LDS_BYTES, stream>>>(x, blob, out, partials);
  vq_fin<<<1, 256, 0, stream>>>(partials, out);
}

// Round 9
// 166.554 us; speedup vs baseline: 1.5432x; 1.0509x over previous
//
#include <hip/hip_runtime.h>

#define BATCH   262144
#define IN_DIM  28
#define HID     128
#define LAT     64
#define NCODES  512
#define NBLK    256             // 1024 rows per block (16 waves x 64 rows)
#define WVS     16
#define NWAVE   (NBLK * WVS)    // 4096

#define BLOB_SHORTS 57344       // bf16 table region (shorts)
#define BLOB_F32    864         // fp32 region (e2 + biases)
#define BLOB_BYTES  (BLOB_SHORTS * 2 + BLOB_F32 * 4)   // 118144
#define ACT_BASE    (BLOB_BYTES / 2)                    // short offset 59072
#define LDS_BYTES   (BLOB_BYTES + WVS * 1024 * 2)       // 150912

typedef short v8s __attribute__((ext_vector_type(8)));
typedef float v4f __attribute__((ext_vector_type(4)));

union v8u { v8s s; uint4 u; };

__device__ __forceinline__ unsigned short f2bf(float f) {   // RNE (prep only)
  unsigned u = __float_as_uint(f);
  u += 0x7fffu + ((u >> 16) & 1u);
  return (unsigned short)(u >> 16);
}
// truncating f32->bf16 (validated r7/r8: absmax 0.0015 < thr 0.020)
__device__ __forceinline__ unsigned short hi16(float f) {
  return (unsigned short)(__float_as_uint(f) >> 16);
}
// pack two truncated bf16 (lo, hi) in ONE v_perm_b32
__device__ __forceinline__ unsigned pk(float hi, float lo) {
  return __builtin_amdgcn_perm(__float_as_uint(hi), __float_as_uint(lo), 0x07060302u);
}

// Bank-swizzled table offset (shorts): 16B col-blocks XOR-permuted by row.
__device__ __forceinline__ int toff(int base, int row, int col, int SB) {
  return base + row * (SB * 8) + ((((col >> 3) ^ row) & (SB - 1)) << 3) + (col & 7);
}
// XOR-swizzled 16x64 half-tile (per-wave 2 KB act buffer), offsets in shorts.
__device__ __forceinline__ int hswz(int row, int col) {   // row 0..15, col 0..63
  int g = col >> 3;                                       // 0..7
  return (g * 16 + ((row ^ g) & 15)) * 8 + (col & 7);
}

// Blob layout (short offsets):
//   lw1  @0      [128 n][32 k]  SB=4   enc_w1^T (k>=28 zero)
//   lw2  @4096   [64 n][128 k]  SB=16  enc_w2^T
//   lcb  @12288  [512 c][64 d]  SB=8   bf16(-2*codebook)   <-- scaled
//   ld1  @45056  [128 n][64 k]  SB=8   bf16(-0.5*dec_w1^T) <-- scaled (cancels)
//   ld2  @53248  [32 n][128 k]  SB=16  dec_w2^T (n>=28 zero)
// fp32 @ byte 114688: e2[512], b1[128], b2[64], db1[128], db2[32 pad0]
__global__ __launch_bounds__(256) void vq_prep(
    const float* __restrict__ ew1, const float* __restrict__ eb1,
    const float* __restrict__ ew2, const float* __restrict__ eb2,
    const float* __restrict__ cb,  const float* __restrict__ dw1,
    const float* __restrict__ db1, const float* __restrict__ dw2,
    const float* __restrict__ db2,
    unsigned short* __restrict__ blob) {
  int i = blockIdx.x * 256 + threadIdx.x;
  float* fb = (float*)(blob + BLOB_SHORTS);
  if (i < 4096) {                       // lw1
    int row = i >> 5, col = i & 31;
    float v = (col < IN_DIM) ? ew1[col * HID + row] : 0.f;
    blob[toff(0, row, col, 4)] = f2bf(v);
  } else if (i < 12288) {               // lw2
    int j = i - 4096; int row = j >> 7, col = j & 127;
    blob[toff(4096, row, col, 16)] = f2bf(ew2[col * LAT + row]);
  } else if (i < 45056) {               // lcb = -2*cb
    int j = i - 12288; int row = j >> 6, col = j & 63;
    blob[toff(12288, row, col, 8)] = f2bf(-2.0f * cb[j]);
  } else if (i < 53248) {               // ld1 = -0.5*dec_w1^T  (exact scale)
    int j = i - 45056; int row = j >> 6, col = j & 63;
    blob[toff(45056, row, col, 8)] = f2bf(-0.5f * dw1[col * HID + row]);
  } else if (i < 57344) {               // ld2
    int j = i - 53248; int row = j >> 7, col = j & 127;
    float v = (row < IN_DIM) ? dw2[col * IN_DIM + row] : 0.f;
    blob[toff(53248, row, col, 16)] = f2bf(v);
  } else if (i < 57344 + 512) {         // e2
    int c = i - 57344;
    float s = 0.f;
    for (int d = 0; d < LAT; ++d) { float v = cb[c * LAT + d]; s += v * v; }
    fb[c] = s;
  } else if (i < 57344 + 640) {
    fb[i - 57344] = eb1[i - 57344 - 512];
  } else if (i < 57344 + 704) {
    fb[i - 57344] = eb2[i - 57344 - 640];
  } else if (i < 57344 + 832) {
    fb[i - 57344] = db1[i - 57344 - 704];
  } else if (i < 57344 + 864) {
    int k = i - 57344 - 832;
    fb[i - 57344] = (k < IN_DIM) ? db2[k] : 0.f;
  }
}

// ---------------- fused main kernel ----------------
// Tables in LDS (r5 win). Round-9: 1024-thread blocks = 16 waves at the SAME
// 150912-B LDS footprint -> 4 waves/SIMD (was 2). Enabled by shrinking the
// per-wave act buffer 4 KB -> 2 KB: H (16x128) and HD transforms run in two
// 64-col halves through a 16x64 buffer, with stage-2/stage-6 K-accumulation
// interleaved per half (same DS op count, +2 LDS round-trips/tile — hidden
// by doubled TLP). Per-tile serial chain kept in r6 form (r8's argmin
// sharing regressed: latency-bound, not DS-count-bound at 2 waves/SIMD).
__global__ __launch_bounds__(1024) void vq_main(
    const float* __restrict__ x,
    const unsigned short* __restrict__ blob,
    float* __restrict__ out, float* __restrict__ partials) {

  extern __shared__ __align__(16) char smem[];
  unsigned short* L  = (unsigned short*)smem;
  float*          LF = (float*)(smem + BLOB_SHORTS * 2);

  const int tid  = threadIdx.x;
  const int wave = tid >> 6;
  const int lane = tid & 63;
  const int quad = lane >> 4;
  const int lm   = lane & 15;

  // ---- stage tables into LDS (one-time) ----
  {
    const float4* src = (const float4*)blob;
    float4* dst = (float4*)smem;
#pragma unroll
    for (int it = 0; it < 8; ++it) {
      int idx = it * 1024 + tid;
      if (idx < BLOB_BYTES / 16) dst[idx] = src[idx];
    }
  }
  __syncthreads();

  unsigned short* A = L + ACT_BASE + wave * 1024;   // 16x64 half-tile buffer
  const int rbase = blockIdx.x * 1024 + wave * 64;
  float racc = 0.f, vqacc = 0.f;

#pragma unroll 1
  for (int t = 0; t < 4; ++t) {
    const int r0 = rbase + t * 16;

    // ---- x load & bf16 pack ----
    v8u a1;
    {
      const float* xp = x + (size_t)(r0 + lm) * IN_DIM + quad * 8;
      float4 v0 = *(const float4*)xp;
      float4 v1 = {0.f, 0.f, 0.f, 0.f};
      if (quad != 3) v1 = *(const float4*)(xp + 4);
      a1.u.x = pk(v0.y, v0.x); a1.u.y = pk(v0.w, v0.z);
      a1.u.z = pk(v1.y, v1.x); a1.u.w = pk(v1.w, v1.z);
    }

    // ---- stages 1+2, two 64-col halves through the 2 KB buffer ----
    v4f accz[4];
#pragma unroll
    for (int nt2 = 0; nt2 < 4; ++nt2) {
      float bv = LF[640 + nt2 * 16 + lm];
      accz[nt2] = (v4f){bv, bv, bv, bv};
    }
#pragma unroll
    for (int h = 0; h < 2; ++h) {
      // stage 1 for H cols [64h, 64h+64)
#pragma unroll
      for (int j = 0; j < 4; ++j) {
        int nt = 4 * h + j;
        int row = nt * 16 + lm;
        v8s frag = *(const v8s*)&L[toff(0, row, quad * 8, 4)];
        float bv = LF[512 + row];
        v4f seed = {bv, bv, bv, bv};
        v4f acc = __builtin_amdgcn_mfma_f32_16x16x32_bf16(a1.s, frag, seed, 0, 0, 0);
#pragma unroll
        for (int r = 0; r < 4; ++r)
          A[hswz(quad * 4 + r, j * 16 + lm)] = hi16(fmaxf(acc[r], 0.f));
      }
      // A-frags for this half (k = 64h .. 64h+63)
      v8s ha0 = *(const v8s*)&A[hswz(lm, quad * 8)];
      v8s ha1 = *(const v8s*)&A[hswz(lm, 32 + quad * 8)];
      // stage-2 partial accumulation: ks = 2h, 2h+1
#pragma unroll
      for (int nt2 = 0; nt2 < 4; ++nt2) {
        int row = nt2 * 16 + lm;
        v8s f0 = *(const v8s*)&L[toff(4096, row, (2 * h) * 32 + quad * 8, 16)];
        accz[nt2] = __builtin_amdgcn_mfma_f32_16x16x32_bf16(ha0, f0, accz[nt2], 0, 0, 0);
        v8s f1 = *(const v8s*)&L[toff(4096, row, (2 * h + 1) * 32 + quad * 8, 16)];
        accz[nt2] = __builtin_amdgcn_mfma_f32_16x16x32_bf16(ha1, f1, accz[nt2], 0, 0, 0);
      }
    }

    // ---- z (16x64) -> buffer; z2 partial; A-frags ----
    float z2p[4];
#pragma unroll
    for (int nt2 = 0; nt2 < 4; ++nt2)
#pragma unroll
      for (int r = 0; r < 4; ++r)
        A[hswz(quad * 4 + r, nt2 * 16 + lm)] = hi16(accz[nt2][r]);
#pragma unroll
    for (int r = 0; r < 4; ++r)
      z2p[r] = accz[0][r] * accz[0][r] + accz[1][r] * accz[1][r]
             + accz[2][r] * accz[2][r] + accz[3][r] * accz[3][r];
    v8s za0 = *(const v8s*)&A[hswz(lm, quad * 8)];
    v8s za1 = *(const v8s*)&A[hswz(lm, 32 + quad * 8)];

    // ---- argmin: dist = e2 + z.(-2e), per tile (r6 form) ----
    float bd[4]; int bc[4];
#pragma unroll
    for (int r = 0; r < 4; ++r) { bd[r] = 3.4e38f; bc[r] = 0x7fffffff; }
#pragma unroll 4
    for (int ct = 0; ct < 32; ++ct) {
      int row = ct * 16 + lm;
      v8s cb0 = *(const v8s*)&L[toff(12288, row, quad * 8, 8)];
      v8s cb1 = *(const v8s*)&L[toff(12288, row, 32 + quad * 8, 8)];
      float ev = LF[row];
      v4f seed = {ev, ev, ev, ev};
      v4f acc = __builtin_amdgcn_mfma_f32_16x16x32_bf16(za0, cb0, seed, 0, 0, 0);
      acc = __builtin_amdgcn_mfma_f32_16x16x32_bf16(za1, cb1, acc, 0, 0, 0);
#pragma unroll
      for (int r = 0; r < 4; ++r)
        if (acc[r] < bd[r]) { bd[r] = acc[r]; bc[r] = row; }   // ascending -> lowest idx on tie
    }

    // ---- 16-lane reduce (argmin + z2), vq partial, idx broadcast ----
#pragma unroll
    for (int off = 1; off < 16; off <<= 1) {
#pragma unroll
      for (int r = 0; r < 4; ++r) {
        float od = __shfl_xor(bd[r], off, 64);
        int   oc = __shfl_xor(bc[r], off, 64);
        if (od < bd[r] || (od == bd[r] && oc < bc[r])) { bd[r] = od; bc[r] = oc; }
        z2p[r] += __shfl_xor(z2p[r], off, 64);
      }
    }
    if (lm == 0) {
#pragma unroll
      for (int r = 0; r < 4; ++r) vqacc += z2p[r] + bd[r];   // ||z-q||^2
    }
    int i0 = __shfl(bc[0], (lm >> 2) << 4, 64);
    int i1 = __shfl(bc[1], (lm >> 2) << 4, 64);
    int i2 = __shfl(bc[2], (lm >> 2) << 4, 64);
    int i3 = __shfl(bc[3], (lm >> 2) << 4, 64);
    int sel = lm & 3;
    int idxv = sel == 0 ? i0 : sel == 1 ? i1 : sel == 2 ? i2 : i3;

    // ---- stages 5+6, two 64-col halves; A-op = -2q, ld1 pre-scaled -0.5 ----
    v8s qa0 = *(const v8s*)&L[toff(12288, idxv, quad * 8, 8)];
    v8s qa1 = *(const v8s*)&L[toff(12288, idxv, 32 + quad * 8, 8)];
    v4f a6[2];
#pragma unroll
    for (int nt6 = 0; nt6 < 2; ++nt6) {
      float bv = LF[832 + nt6 * 16 + lm];
      a6[nt6] = (v4f){bv, bv, bv, bv};
    }
#pragma unroll
    for (int h = 0; h < 2; ++h) {
      // stage 5 for HD cols [64h, 64h+64)
#pragma unroll
      for (int j = 0; j < 4; ++j) {
        int nt = 4 * h + j;
        int row = nt * 16 + lm;
        v8s b0 = *(const v8s*)&L[toff(45056, row, quad * 8, 8)];
        v8s b1 = *(const v8s*)&L[toff(45056, row, 32 + quad * 8, 8)];
        float bv = LF[704 + row];
        v4f seed = {bv, bv, bv, bv};
        v4f acc = __builtin_amdgcn_mfma_f32_16x16x32_bf16(qa0, b0, seed, 0, 0, 0);
        acc = __builtin_amdgcn_mfma_f32_16x16x32_bf16(qa1, b1, acc, 0, 0, 0);
#pragma unroll
        for (int r = 0; r < 4; ++r)
          A[hswz(quad * 4 + r, j * 16 + lm)] = hi16(fmaxf(acc[r], 0.f));
      }
      v8s hd0 = *(const v8s*)&A[hswz(lm, quad * 8)];
      v8s hd1 = *(const v8s*)&A[hswz(lm, 32 + quad * 8)];
      // stage-6 partial accumulation: ks = 2h, 2h+1
#pragma unroll
      for (int nt6 = 0; nt6 < 2; ++nt6) {
        int row = nt6 * 16 + lm;
        v8s f0 = *(const v8s*)&L[toff(53248, row, (2 * h) * 32 + quad * 8, 16)];
        a6[nt6] = __builtin_amdgcn_mfma_f32_16x16x32_bf16(hd0, f0, a6[nt6], 0, 0, 0);
        v8s f1 = *(const v8s*)&L[toff(53248, row, (2 * h + 1) * 32 + quad * 8, 16)];
        a6[nt6] = __builtin_amdgcn_mfma_f32_16x16x32_bf16(hd1, f1, a6[nt6], 0, 0, 0);
      }
    }

    // ---- store recon + loss partial ----
#pragma unroll
    for (int nt6 = 0; nt6 < 2; ++nt6) {
      int n = nt6 * 16 + lm;
      bool valid = (n < IN_DIM);
#pragma unroll
      for (int r = 0; r < 4; ++r) {
        float rec = a6[nt6][r];
        if (valid) {
          size_t o = (size_t)(r0 + quad * 4 + r) * IN_DIM + n;
          out[o] = rec;
          float dv = rec - x[o];
          racc += dv * dv;
        }
      }
    }
  }

  // ---- per-wave butterfly, per-wave partial store (no atomics) ----
#pragma unroll
  for (int off = 1; off < 64; off <<= 1) {
    racc  += __shfl_xor(racc, off, 64);
    vqacc += __shfl_xor(vqacc, off, 64);
  }
  if (lane == 0) {
    size_t w = (size_t)blockIdx.x * WVS + wave;
    partials[w * 2]     = racc;
    partials[w * 2 + 1] = vqacc;
  }
}

// ---------------- finalize: reduce per-wave partials, write scalars ----------------
__global__ __launch_bounds__(256) void vq_fin(const float* __restrict__ partials,
                                              float* __restrict__ out) {
  float r = 0.f, v = 0.f;
  for (int i = threadIdx.x; i < NWAVE; i += 256) {
    r += partials[2 * i];
    v += partials[2 * i + 1];
  }
#pragma unroll
  for (int off = 1; off < 64; off <<= 1) {
    r += __shfl_xor(r, off, 64);
    v += __shfl_xor(v, off, 64);
  }
  __shared__ float s[4][2];
  int w = threadIdx.x >> 6;
  if ((threadIdx.x & 63) == 0) { s[w][0] = r; s[w][1] = v; }
  __syncthreads();
  if (threadIdx.x == 0) {
    float R = s[0][0] + s[1][0] + s[2][0] + s[3][0];
    float V = s[0][1] + s[1][1] + s[2][1] + s[3][1];
    out[7340032] = R * (1.0f / 7340032.0f);          // recon_loss = S / (B*28)
    out[7340033] = V * (1.25f / 16777216.0f);        // vq_loss = 1.25 * S / (B*64)
  }
}

extern "C" void kernel_launch(void* const* d_in, const int* in_sizes, int n_in,
                              void* d_out, int out_size, void* d_ws, size_t ws_size,
                              hipStream_t stream) {
  const float* x   = (const float*)d_in[0];
  const float* ew1 = (const float*)d_in[1];
  const float* eb1 = (const float*)d_in[2];
  const float* ew2 = (const float*)d_in[3];
  const float* eb2 = (const float*)d_in[4];
  const float* cb  = (const float*)d_in[5];
  const float* dw1 = (const float*)d_in[6];
  const float* db1 = (const float*)d_in[7];
  const float* dw2 = (const float*)d_in[8];
  const float* db2 = (const float*)d_in[9];

  char* ws = (char*)d_ws;
  unsigned short* blob = (unsigned short*)(ws + 0);   // 118144 B
  float* partials = (float*)(ws + 118272);            // 32768 B (4096*2 f32)

  float* out = (float*)d_out;

  // allow >64 KB dynamic LDS (gfx950 workgroup max is 160 KB)
  (void)hipFuncSetAttribute((const void*)vq_main,
                            hipFuncAttributeMaxDynamicSharedMemorySize, LDS_BYTES);

  vq_prep<<<228, 256, 0, stream>>>(ew1, eb1, ew2, eb2, cb, dw1, db1, dw2, db2, blob);
  vq_main<<<NBLK, 1024, LDS_BYTES, stream>>>(x, blob, out, partials);
  vq_fin<<<1, 256, 0, stream>>>(partials, out);
}